// Round 1
// baseline (28655.530 us; speedup 1.0000x reference)
//
#include <hip/hip_runtime.h>
#include <math.h>

// ---------------- constants ----------------
static constexpr int CB    = 1;      // batch
static constexpr int CT    = 8;      // time steps
static constexpr int SLAT  = 256;
static constexpr int CDIN  = 768;
static constexpr int CD    = 1024;
static constexpr int CA    = 8;
static constexpr int CREG  = 4;
static constexpr int CDEPTH= 12;
static constexpr int CH    = 16;
static constexpr int CHD   = 64;
static constexpr int CDFF  = 4096;
static constexpr int CCTX  = 10;
static constexpr int CSTOT = 2 + CREG + SLAT;   // 262
static constexpr int NTOK  = CB * CT * CSTOT;   // 2096
static constexpr int NLAT  = CB * CT * SLAT;    // 2048

// epilogue modes
enum { EPI_NONE = 0, EPI_BIAS = 1, EPI_BIAS_SILU = 2, EPI_SILU = 3, EPI_MUL = 4, EPI_RESID = 5 };

__device__ __forceinline__ float silu_f(float x) { return x / (1.f + expf(-x)); }

// ---------------- generic f32 GEMM: C[M,N] = epi(A[M,K] @ W[K,N]) ----------------
// tiles 128x128, BK=16, 256 threads, 8x8 per-thread microtile
template<int EPI>
__global__ __launch_bounds__(256) void gemm_f32(
    const float* __restrict__ A, const float* __restrict__ W, float* __restrict__ C,
    int M, int N, int K, const float* __restrict__ bias, const float* __restrict__ other)
{
    constexpr int BM = 128, BN = 128, BK = 16;
    __shared__ float As[BK][BM];
    __shared__ float Bs[BK][BN];

    const int tid = threadIdx.x;
    const int bn = blockIdx.x, bm = blockIdx.y;
    const int row0 = bm * BM, col0 = bn * BN;
    const int tx = tid & 15, ty = tid >> 4;

    float acc[8][8];
#pragma unroll
    for (int i = 0; i < 8; i++)
#pragma unroll
        for (int j = 0; j < 8; j++) acc[i][j] = 0.f;

    for (int k0 = 0; k0 < K; k0 += BK) {
        // load A tile (BM x BK), store transposed As[k][m]
#pragma unroll
        for (int l = 0; l < 2; l++) {
            int f = tid * 2 + l;          // 0..511 float4 ids
            int r = f >> 2;               // 0..127
            int c = (f & 3) * 4;          // 0,4,8,12
            int gr = row0 + r;
            float4 v = make_float4(0.f, 0.f, 0.f, 0.f);
            if (gr < M) v = *reinterpret_cast<const float4*>(&A[(size_t)gr * K + k0 + c]);
            As[c + 0][r] = v.x; As[c + 1][r] = v.y; As[c + 2][r] = v.z; As[c + 3][r] = v.w;
        }
        // load B tile (BK x BN)
#pragma unroll
        for (int l = 0; l < 2; l++) {
            int f = tid * 2 + l;
            int r = f >> 5;               // 0..15
            int c = (f & 31) * 4;         // 0..124
            float4 v = *reinterpret_cast<const float4*>(&W[(size_t)(k0 + r) * N + col0 + c]);
            *reinterpret_cast<float4*>(&Bs[r][c]) = v;
        }
        __syncthreads();
#pragma unroll
        for (int kk = 0; kk < BK; kk++) {
            float4 a0 = *reinterpret_cast<const float4*>(&As[kk][ty * 8]);
            float4 a1 = *reinterpret_cast<const float4*>(&As[kk][ty * 8 + 4]);
            float4 b0 = *reinterpret_cast<const float4*>(&Bs[kk][tx * 8]);
            float4 b1 = *reinterpret_cast<const float4*>(&Bs[kk][tx * 8 + 4]);
            float a[8] = {a0.x, a0.y, a0.z, a0.w, a1.x, a1.y, a1.z, a1.w};
            float b[8] = {b0.x, b0.y, b0.z, b0.w, b1.x, b1.y, b1.z, b1.w};
#pragma unroll
            for (int i = 0; i < 8; i++)
#pragma unroll
                for (int j = 0; j < 8; j++) acc[i][j] = fmaf(a[i], b[j], acc[i][j]);
        }
        __syncthreads();
    }

#pragma unroll
    for (int i = 0; i < 8; i++) {
        int gr = row0 + ty * 8 + i;
        if (gr >= M) continue;
#pragma unroll
        for (int j = 0; j < 8; j++) {
            int gc = col0 + tx * 8 + j;
            float v = acc[i][j];
            size_t oidx = (size_t)gr * N + gc;
            if (EPI == EPI_BIAS)       v = v + bias[gc];
            else if (EPI == EPI_BIAS_SILU) v = silu_f(v + bias[gc]);
            else if (EPI == EPI_SILU)  v = silu_f(v);
            else if (EPI == EPI_MUL)   v = v * other[oidx];
            else if (EPI == EPI_RESID) v = v + other[oidx];
            C[oidx] = v;
        }
    }
}

// ---------------- RMSNorm over D=1024, one block per row ----------------
__global__ __launch_bounds__(256) void rms_rows(
    const float* __restrict__ in, float* __restrict__ out, const float* __restrict__ w, int latmode)
{
    int row = blockIdx.x;
    int t = threadIdx.x;
    size_t ir;
    if (latmode) { int tt = row >> 8, s = row & 255; ir = (size_t)(tt * CSTOT + 6 + s) * CD; }
    else ir = (size_t)row * CD;
    const float4* ip = reinterpret_cast<const float4*>(in + ir);
    float4 v = ip[t];
    float ss = v.x * v.x + v.y * v.y + v.z * v.z + v.w * v.w;
#pragma unroll
    for (int o = 32; o; o >>= 1) ss += __shfl_xor(ss, o);
    __shared__ float red[4];
    if ((t & 63) == 0) red[t >> 6] = ss;
    __syncthreads();
    float total = red[0] + red[1] + red[2] + red[3];
    float scale = rsqrtf(total * (1.f / 1024.f) + 1e-6f);
    const float4* wp = reinterpret_cast<const float4*>(w);
    float4 wv = wp[t];
    float4 o4 = make_float4(v.x * scale * wv.x, v.y * scale * wv.y, v.z * scale * wv.z, v.w * scale * wv.w);
    reinterpret_cast<float4*>(out + (size_t)row * CD)[t] = o4;
}

// ---------------- per-head QK RMSNorm + RoPE (in place) ----------------
__global__ __launch_bounds__(64) void qknorm_rope(
    float* __restrict__ Q, float* __restrict__ K,
    const float* __restrict__ qn, const float* __restrict__ kn, int temporal)
{
    int bid = blockIdx.x;           // r*H + h
    int which = blockIdx.y;         // 0 = Q, 1 = K
    int r = bid >> 4, h = bid & 15;
    float* X = which ? K : Q;
    const float* w = which ? kn : qn;
    int d = threadIdx.x;            // 0..63
    float* p = X + (size_t)r * CD + h * CHD;
    float v = p[d];
    float ss = v * v;
#pragma unroll
    for (int o = 32; o; o >>= 1) ss += __shfl_xor(ss, o);
    v = v * rsqrtf(ss * (1.f / 64.f) + 1e-6f) * w[d];
    int pos = temporal ? (r / CSTOT) : (r % CSTOT);
    float inv = expf(-logf(10000.f) * (float)(d & 31) * (1.f / 32.f));
    float ang = (float)pos * inv;
    float partner = __shfl_xor(v, 32);
    float rot = (d < 32) ? -partner : partner;
    p[d] = v * cosf(ang) + rot * sinf(ang);
}

// ---------------- spatial attention: full 262x262 per (t,h), 1 thread = 1 query row ----------------
__global__ __launch_bounds__(320) void attn_spatial(
    const float* __restrict__ Q, const float* __restrict__ K, const float* __restrict__ V,
    float* __restrict__ O)
{
    int t = blockIdx.x >> 4, h = blockIdx.x & 15;
    int q = threadIdx.x;
    if (q >= CSTOT) return;
    size_t base = (size_t)t * CSTOT * CD + h * CHD;
    const float4* qp = reinterpret_cast<const float4*>(Q + base + (size_t)q * CD);
    float4 qr[16];
#pragma unroll
    for (int i = 0; i < 16; i++) qr[i] = qp[i];
    float4 o[16];
#pragma unroll
    for (int i = 0; i < 16; i++) o[i] = make_float4(0.f, 0.f, 0.f, 0.f);
    float m = -1e30f, l = 0.f;
    for (int k = 0; k < CSTOT; k++) {
        const float4* kp = reinterpret_cast<const float4*>(K + base + (size_t)k * CD);
        float dot = 0.f;
#pragma unroll
        for (int i = 0; i < 16; i++) {
            float4 kv = kp[i];
            dot += qr[i].x * kv.x + qr[i].y * kv.y + qr[i].z * kv.z + qr[i].w * kv.w;
        }
        dot *= 0.125f;                       // HD^-0.5
        dot = 50.f * tanhf(dot * 0.02f);     // softcap
        float mn = fmaxf(m, dot);
        float corr = expf(m - mn);
        float pw = expf(dot - mn);
        m = mn;
        l = l * corr + pw;
        const float4* vp = reinterpret_cast<const float4*>(V + base + (size_t)k * CD);
#pragma unroll
        for (int i = 0; i < 16; i++) {
            float4 vv = vp[i];
            o[i].x = o[i].x * corr + pw * vv.x;
            o[i].y = o[i].y * corr + pw * vv.y;
            o[i].z = o[i].z * corr + pw * vv.z;
            o[i].w = o[i].w * corr + pw * vv.w;
        }
    }
    float invl = 1.f / l;
    float4* op = reinterpret_cast<float4*>(O + base + (size_t)q * CD);
#pragma unroll
    for (int i = 0; i < 16; i++)
        op[i] = make_float4(o[i].x * invl, o[i].y * invl, o[i].z * invl, o[i].w * invl);
}

// ---------------- temporal attention: seq len T=8 per (s,h), 1 thread per (s,h,qt) ----------------
__global__ __launch_bounds__(256) void attn_temporal(
    const float* __restrict__ Q, const float* __restrict__ K, const float* __restrict__ V,
    const int* __restrict__ indep, float* __restrict__ O)
{
    int gid = blockIdx.x * 256 + threadIdx.x;
    if (gid >= CSTOT * CH * CT) return;
    int qt = gid & 7;
    int h = (gid >> 3) & 15;
    int s = gid >> 7;
    size_t rq = (size_t)(qt * CSTOT + s) * CD + h * CHD;
    const float4* qp = reinterpret_cast<const float4*>(Q + rq);
    float4 qr[16];
#pragma unroll
    for (int i = 0; i < 16; i++) qr[i] = qp[i];
    bool ind = (indep[qt] != 0);
    float m = -1e30f, l = 0.f;
    float4 o[16];
#pragma unroll
    for (int i = 0; i < 16; i++) o[i] = make_float4(0.f, 0.f, 0.f, 0.f);
    for (int kt = 0; kt <= qt; kt++) {
        if (ind && kt != qt) continue;
        if (qt - kt > CCTX) continue;
        size_t rk = (size_t)(kt * CSTOT + s) * CD + h * CHD;
        const float4* kp = reinterpret_cast<const float4*>(K + rk);
        float dot = 0.f;
#pragma unroll
        for (int i = 0; i < 16; i++) {
            float4 kv = kp[i];
            dot += qr[i].x * kv.x + qr[i].y * kv.y + qr[i].z * kv.z + qr[i].w * kv.w;
        }
        dot *= 0.125f;
        dot = 50.f * tanhf(dot * 0.02f);
        float mn = fmaxf(m, dot);
        float corr = expf(m - mn);
        float pw = expf(dot - mn);
        m = mn;
        l = l * corr + pw;
        const float4* vp = reinterpret_cast<const float4*>(V + rk);
#pragma unroll
        for (int i = 0; i < 16; i++) {
            float4 vv = vp[i];
            o[i].x = o[i].x * corr + pw * vv.x;
            o[i].y = o[i].y * corr + pw * vv.y;
            o[i].z = o[i].z * corr + pw * vv.z;
            o[i].w = o[i].w * corr + pw * vv.w;
        }
    }
    float invl = 1.f / l;
    float4* op = reinterpret_cast<float4*>(O + rq);
#pragma unroll
    for (int i = 0; i < 16; i++)
        op[i] = make_float4(o[i].x * invl, o[i].y * invl, o[i].z * invl, o[i].w * invl);
}

// ---------------- tiny embedding kernels ----------------
__global__ void sig_emb_kernel(const float* __restrict__ sl, float* __restrict__ emb)
{
    int tid = blockIdx.x * 256 + threadIdx.x;   // 8*128
    if (tid >= CT * 128) return;
    int t = tid >> 7, j = tid & 127;
    float tv = sl[t] * 1000.f;
    float fr = expf(-logf(10000.f) * (float)j * (1.f / 128.f));
    float ang = tv * fr;
    emb[t * 256 + j] = cosf(ang);
    emb[t * 256 + 128 + j] = sinf(ang);
}

__global__ void act_emb_kernel(const float* __restrict__ actions, const int* __restrict__ use,
                               const float* __restrict__ base, const float* __restrict__ actw,
                               const float* __restrict__ actb, float* __restrict__ act)
{
    int tid = blockIdx.x * 256 + threadIdx.x;   // 8*1024
    if (tid >= CT * CD) return;
    int t = tid >> 10, d = tid & 1023;
    float v = base[d];
    if (use[t]) {
        float s = actb[d];
#pragma unroll
        for (int a = 0; a < CA; a++) s += actions[t * CA + a] * actw[a * CD + d];
        v += s;
    }
    act[tid] = v;
}

__global__ void assemble_kernel(const float* __restrict__ xin, const float* __restrict__ sig,
                                const float* __restrict__ act, const float* __restrict__ regs,
                                float* __restrict__ X)
{
    int idx = blockIdx.x * 256 + threadIdx.x;   // NTOK*D
    if (idx >= NTOK * CD) return;
    int d = idx & 1023;
    int r = idx >> 10;
    int t = r / CSTOT, s = r % CSTOT;
    float v;
    if (s == 0) v = sig[t * CD + d];
    else if (s == 1) v = act[t * CD + d];
    else if (s < 6) v = regs[(s - 2) * CD + d];
    else v = xin[((size_t)t * SLAT + (s - 6)) * CD + d];
    X[idx] = v;
}

// ---------------- GEMM launcher ----------------
template<int EPI>
static inline void gemm(const float* A, const float* W, float* C, int M, int N, int K,
                        const float* bias, const float* other, hipStream_t s)
{
    dim3 g(N / 128, (M + 127) / 128);
    gemm_f32<EPI><<<g, 256, 0, s>>>(A, W, C, M, N, K, bias, other);
}

// ---------------- entry ----------------
extern "C" void kernel_launch(void* const* d_in, const int* in_sizes, int n_in,
                              void* d_out, int out_size, void* d_ws, size_t ws_size,
                              hipStream_t stream)
{
    (void)in_sizes; (void)n_in; (void)out_size; (void)ws_size;

    const float* noisy       = (const float*)d_in[0];
    const float* sig_lv      = (const float*)d_in[1];
    const float* actions     = (const float*)d_in[2];
    const int*   use_actions = (const int*)  d_in[3];
    const int*   indep       = (const int*)  d_in[4];
    const float* in_w        = (const float*)d_in[5];
    const float* sig_w1      = (const float*)d_in[6];
    const float* sig_b1      = (const float*)d_in[7];
    const float* sig_w2      = (const float*)d_in[8];
    const float* sig_b2      = (const float*)d_in[9];
    const float* base_action = (const float*)d_in[10];
    const float* act_w       = (const float*)d_in[11];
    const float* act_b       = (const float*)d_in[12];
    const float* registers   = (const float*)d_in[13];
    const float* ln1_w       = (const float*)d_in[14];
    const float* ln2_w       = (const float*)d_in[15];
    const float* wq          = (const float*)d_in[16];
    const float* wk          = (const float*)d_in[17];
    const float* wv          = (const float*)d_in[18];
    const float* wo          = (const float*)d_in[19];
    const float* qn_w        = (const float*)d_in[20];
    const float* kn_w        = (const float*)d_in[21];
    const float* w1          = (const float*)d_in[22];
    const float* w2          = (const float*)d_in[23];
    const float* w3          = (const float*)d_in[24];
    const float* fin_w       = (const float*)d_in[25];
    const float* out_w       = (const float*)d_in[26];
    const float* out_b       = (const float*)d_in[27];

    float* ws = (float*)d_ws;
    size_t off = 0;
    float* XIN = ws + off; off += (size_t)NLAT * CD;        // 2048x1024 (reused for final lat-norm)
    float* X   = ws + off; off += (size_t)NTOK * CD;
    float* XN  = ws + off; off += (size_t)NTOK * CD;        // also used as attention-O buffer
    float* Qb  = ws + off; off += (size_t)NTOK * CD;
    float* Kb  = ws + off; off += (size_t)NTOK * CD;
    float* Vb  = ws + off; off += (size_t)NTOK * CD;
    float* FF1 = ws + off; off += (size_t)NTOK * CDFF;
    float* EMB = ws + off; off += CT * 256;
    float* SGH = ws + off; off += CT * CD;
    float* SGE = ws + off; off += CT * CD;
    float* ACT = ws + off; off += CT * CD;

    // ---- embeddings / token assembly ----
    gemm<EPI_NONE>(noisy, in_w, XIN, NLAT, CD, CDIN, nullptr, nullptr, stream);
    sig_emb_kernel<<<4, 256, 0, stream>>>(sig_lv, EMB);
    gemm<EPI_BIAS_SILU>(EMB, sig_w1, SGH, CT, CD, 256, sig_b1, nullptr, stream);
    gemm<EPI_BIAS>(SGH, sig_w2, SGE, CT, CD, CD, sig_b2, nullptr, stream);
    act_emb_kernel<<<(CT * CD + 255) / 256, 256, 0, stream>>>(actions, use_actions, base_action, act_w, act_b, ACT);
    assemble_kernel<<<(NTOK * CD + 255) / 256, 256, 0, stream>>>(XIN, SGE, ACT, registers, X);

    // ---- transformer blocks ----
    for (int i = 0; i < CDEPTH; i++) {
        int temporal = (i % 4 == 0 && i != 0 && i != CDEPTH - 1) ? 1 : 0;   // layers 4, 8
        const float* wqi = wq + (size_t)i * CD * CD;
        const float* wki = wk + (size_t)i * CD * CD;
        const float* wvi = wv + (size_t)i * CD * CD;
        const float* woi = wo + (size_t)i * CD * CD;
        const float* w1i = w1 + (size_t)i * CD * CDFF;
        const float* w2i = w2 + (size_t)i * CD * CDFF;
        const float* w3i = w3 + (size_t)i * CDFF * CD;

        rms_rows<<<NTOK, 256, 0, stream>>>(X, XN, ln1_w + i * CD, 0);
        gemm<EPI_NONE>(XN, wqi, Qb, NTOK, CD, CD, nullptr, nullptr, stream);
        gemm<EPI_NONE>(XN, wki, Kb, NTOK, CD, CD, nullptr, nullptr, stream);
        gemm<EPI_NONE>(XN, wvi, Vb, NTOK, CD, CD, nullptr, nullptr, stream);
        qknorm_rope<<<dim3(NTOK * CH, 2), 64, 0, stream>>>(Qb, Kb, qn_w + i * CHD, kn_w + i * CHD, temporal);
        if (temporal)
            attn_temporal<<<(CSTOT * CH * CT + 255) / 256, 256, 0, stream>>>(Qb, Kb, Vb, indep, XN);
        else
            attn_spatial<<<CT * CH, 320, 0, stream>>>(Qb, Kb, Vb, XN);
        gemm<EPI_RESID>(XN, woi, X, NTOK, CD, CD, nullptr, X, stream);

        rms_rows<<<NTOK, 256, 0, stream>>>(X, XN, ln2_w + i * CD, 0);
        gemm<EPI_SILU>(XN, w1i, FF1, NTOK, CDFF, CD, nullptr, nullptr, stream);
        gemm<EPI_MUL>(XN, w2i, FF1, NTOK, CDFF, CD, nullptr, FF1, stream);
        gemm<EPI_RESID>(FF1, w3i, X, NTOK, CD, CDFF, nullptr, X, stream);
    }

    // ---- final norm + out projection ----
    rms_rows<<<NLAT, 256, 0, stream>>>(X, XIN, fin_w, 1);
    gemm<EPI_BIAS>(XIN, out_w, (float*)d_out, NLAT, CDIN, CD, out_b, nullptr, stream);
}